// Round 2
// baseline (357.507 us; speedup 1.0000x reference)
//
#include <hip/hip_runtime.h>
#include <hip/hip_bf16.h>

// CrossAttention R7 = R6 + race hardening (no structural changes).
// (Resubmitted unchanged for R8: previous round was an infra failure —
//  "MI355X container failed twice" — the kernel never ran.)
//  - R6 failed the POST-TIMING recheck (first check passed, tripwire passed):
//    a scheduling-dependent race, not a logic bug. Two latent hazards fixed:
//    (a) loop barriers now carry an EXPLICIT "s_waitcnt vmcnt(0) lgkmcnt(0)"
//        so no ds_read/global_load_lds can remain outstanding across
//        s_barrier (the single-barrier double-buffer pattern is only safe if
//        the drain is guaranteed; previously we relied on the compiler).
//    (b) attn's P tile is written via uint2* and read via bf16x8* (TBAA says
//        no-alias): an explicit compiler memory barrier now pins the order.
//  - gemm128: double-buffered K-loop (preload + prefetch-next + ONE barrier/iter).
//  - K-proj and V-proj merged into one N=2048 GEMM over contiguous WkvT.
//  - attn: R4 structure (102us, MfmaUtil 29%), denominator sums untruncated exp2.

typedef short bf16x8 __attribute__((ext_vector_type(8)));
typedef float f32x4 __attribute__((ext_vector_type(4)));

__device__ __forceinline__ short f2s(float f) {
    __hip_bfloat16 h = __float2bfloat16(f);
    return __builtin_bit_cast(short, h);
}

__device__ __forceinline__ f32x4 mfma16(bf16x8 a, bf16x8 b, f32x4 c) {
    return __builtin_amdgcn_mfma_f32_16x16x32_bf16(a, b, c, 0, 0, 0);
}

__device__ __forceinline__ void gload16(short* lds, const short* g) {
    __builtin_amdgcn_global_load_lds((const __attribute__((address_space(1))) void*)g,
                                     (__attribute__((address_space(3))) void*)lds,
                                     16, 0, 0);
}

// Barrier with guaranteed counter drain: no wave may cross with outstanding
// LDS reads (WAR vs next iter's global_load_lds) or outstanding staging loads
// (RAW for next iter's ds_read). The compiler usually emits exactly this
// before s_barrier; we make it unconditional.
__device__ __forceinline__ void drain_barrier() {
    asm volatile("s_waitcnt vmcnt(0) lgkmcnt(0)" ::: "memory");
    __syncthreads();
}

__device__ __forceinline__ unsigned int fbits(float f) {
    return __builtin_bit_cast(unsigned int, f);
}

// ---------------- prep: fp32 -> bf16 for activations ----------------
__global__ __launch_bounds__(256) void conv_to_bf16(const float* __restrict__ x,
                                                    const float* __restrict__ ctx,
                                                    short* __restrict__ xb,
                                                    short* __restrict__ cb) {
    const size_t NV = 2097152;
    size_t i = (size_t)blockIdx.x * 256 + threadIdx.x;
    const float4* src = (i < NV) ? (const float4*)x : (const float4*)ctx;
    short* dst = (i < NV) ? xb : cb;
    size_t idx = (i < NV) ? i : i - NV;
    float4 v = src[idx];
    short4 o;
    o.x = f2s(v.x); o.y = f2s(v.y); o.z = f2s(v.z); o.w = f2s(v.w);
    ((short4*)dst)[idx] = o;
}

// ---------------- prep: W -> W^T bf16 (K+V halves contiguous in WkvT) ----------------
__global__ __launch_bounds__(256) void transpose_weights(
    const float* __restrict__ q_w, const float* __restrict__ kv_w,
    const float* __restrict__ proj_w,
    short* __restrict__ WqT, short* __restrict__ WkvT, short* __restrict__ WpT) {
    __shared__ float t[32][33];
    const float* src; short* dst; int ld, coff;
    switch (blockIdx.z) {
        case 0:  src = q_w;    dst = WqT;                 ld = 1024; coff = 0;    break;
        case 1:  src = kv_w;   dst = WkvT;                ld = 2048; coff = 0;    break;
        case 2:  src = kv_w;   dst = WkvT + 1024 * 1024;  ld = 2048; coff = 1024; break;
        default: src = proj_w; dst = WpT;                 ld = 1024; coff = 0;    break;
    }
    int n0 = blockIdx.x * 32, k0 = blockIdx.y * 32;
    int tx = threadIdx.x & 31, ty = threadIdx.x >> 5;
    #pragma unroll
    for (int j = 0; j < 32; j += 8)
        t[ty + j][tx] = src[(size_t)(k0 + ty + j) * ld + coff + n0 + tx];
    __syncthreads();
    #pragma unroll
    for (int j = 0; j < 32; j += 8)
        dst[(size_t)(n0 + ty + j) * 1024 + k0 + tx] = f2s(t[tx][ty + j]);
}

// ---------------- GEMM 128x128, K=1024, double-buffered staging ----------------
// MODE 0: Q proj -> per-head LN -> RoPE -> Q[b,h,s,64] bf16 (coalesced via LDS overlay)
// MODE 1: KV proj (N=2048): n0<1024 -> K path (LN -> K[b,h,sc,64]); else V path
//         (V^T[b,h,64,sc] transposed b64 stores)
// MODE 2: out proj -> + bias -> fp32 out
template <int MODE>
__global__ __launch_bounds__(256) void gemm128(
    const short* __restrict__ A,    // [8192][1024] bf16 row-major
    const short* __restrict__ Bt,   // [N][1024] bf16 (N-major, K contiguous)
    const float* __restrict__ ln_scale,
    const float* __restrict__ ln_bias,
    short* __restrict__ outB,
    short* __restrict__ outB2,
    float* __restrict__ outF,
    const float* __restrict__ bias_vec) {
    // staging: 2 bufs x (A 128x32 + B 128x32) = 16384 shorts; epilogue overlay 128x132.
    __shared__ short smem[(MODE <= 1) ? 16896 : 16384];
    const int tid = threadIdx.x;
    const int w = tid >> 6, lane = tid & 63, quad = lane >> 4, l15 = lane & 15;
    const int wr = w & 1, wc = w >> 1;
    const int m0 = blockIdx.y * 128, n0 = blockIdx.x * 128;

    const int srow = lane >> 2, slot = lane & 3;
    const int kslot = (slot ^ ((srow >> 1) & 3)) * 8;  // XOR swizzle: 2-way banks on read
    const short* Ag0 = A + (size_t)(m0 + w * 32 + srow) * 1024 + kslot;
    const short* Ag1 = Ag0 + (size_t)16 * 1024;
    const short* Bg0 = Bt + (size_t)(n0 + w * 32 + srow) * 1024 + kslot;
    const short* Bg1 = Bg0 + (size_t)16 * 1024;
    // wave w stages rows [w*32, w*32+32): 1024 shorts per tile (two 512-short gloads)
    short* Al = smem + w * 1024;           // + buf*8192
    short* Bl = smem + 4096 + w * 1024;    // + buf*8192

    f32x4 acc[4][4];
    #pragma unroll
    for (int r = 0; r < 4; r++)
        #pragma unroll
        for (int c = 0; c < 4; c++) acc[r][c] = f32x4{0.f, 0.f, 0.f, 0.f};

    const int rsw = (l15 >> 1) & 3;
    const int rch = (quad ^ rsw) * 8;

    // preload k-tile 0 into buffer 0
    gload16(Al,       Ag0);
    gload16(Al + 512, Ag1);
    gload16(Bl,       Bg0);
    gload16(Bl + 512, Bg1);
    drain_barrier();

    #pragma unroll 1
    for (int t = 0; t < 32; t++) {
        const int cur = (t & 1) * 8192;
        if (t < 31) {
            const int nxt = 8192 - cur;
            const int k0 = (t + 1) * 32;
            gload16(Al + nxt,       Ag0 + k0);
            gload16(Al + nxt + 512, Ag1 + k0);
            gload16(Bl + nxt,       Bg0 + k0);
            gload16(Bl + nxt + 512, Bg1 + k0);
        }
        bf16x8 af[4], bfr[4];
        #pragma unroll
        for (int rt = 0; rt < 4; rt++)
            af[rt] = *(const bf16x8*)(smem + cur + (wr * 64 + rt * 16 + l15) * 32 + rch);
        #pragma unroll
        for (int ct = 0; ct < 4; ct++)
            bfr[ct] = *(const bf16x8*)(smem + cur + 4096 + (wc * 64 + ct * 16 + l15) * 32 + rch);
        #pragma unroll
        for (int rt = 0; rt < 4; rt++)
            #pragma unroll
            for (int ct = 0; ct < 4; ct++)
                acc[rt][ct] = mfma16(af[rt], bfr[ct], acc[rt][ct]);
        // drains this iter's prefetch (covered by compute) + this wave's LDS
        // reads; explicit so no ds_read can cross the barrier (WAR vs next
        // iter's global_load_lds into the same buffer).
        drain_barrier();
    }

    // epilogue: lane holds C[row = wr*64+rt*16+quad*4+i][col = wc*64+ct*16+l15]
    const bool vpath = (MODE == 1) && (n0 >= 1024);
    if constexpr (MODE == 0 || MODE == 1) {
        if (!vpath) {
            #pragma unroll
            for (int rt = 0; rt < 4; rt++) {
                #pragma unroll
                for (int i = 0; i < 4; i++) {
                    float s = acc[rt][0][i] + acc[rt][1][i] + acc[rt][2][i] + acc[rt][3][i];
                    float q = acc[rt][0][i] * acc[rt][0][i] + acc[rt][1][i] * acc[rt][1][i] +
                              acc[rt][2][i] * acc[rt][2][i] + acc[rt][3][i] * acc[rt][3][i];
                    #pragma unroll
                    for (int off = 1; off < 16; off <<= 1) {
                        s += __shfl_xor(s, off, 64);
                        q += __shfl_xor(q, off, 64);
                    }
                    float mu = s * (1.f / 64.f);
                    float var = q * (1.f / 64.f) - mu * mu;
                    float rs = rsqrtf(var + 1e-5f);
                    float vals[4];
                    #pragma unroll
                    for (int ct = 0; ct < 4; ct++) {
                        int hd = ct * 16 + l15;
                        vals[ct] = (acc[rt][ct][i] - mu) * rs * ln_scale[hd] + ln_bias[hd];
                    }
                    if constexpr (MODE == 0) {  // RoPE pairs (hd, hd+32) = (ct, ct+2)
                        int sp = (m0 + wr * 64 + rt * 16 + quad * 4 + i) & 2047;
                        #pragma unroll
                        for (int ct = 0; ct < 2; ct++) {
                            int hd1 = ct * 16 + l15;
                            float ang = (float)sp * exp2f((float)hd1 * (-13.287712379549449f / 32.f));
                            float sn, cs;
                            sincosf(ang, &sn, &cs);
                            float v1 = vals[ct], v2 = vals[ct + 2];
                            vals[ct]     = v1 * cs - v2 * sn;
                            vals[ct + 2] = v1 * sn + v2 * cs;
                        }
                    }
                    #pragma unroll
                    for (int ct = 0; ct < 4; ct++) acc[rt][ct][i] = vals[ct];
                }
            }
            drain_barrier();
            short* Csm = smem;  // overlay: [128][132] bf16, +4 pad
            #pragma unroll
            for (int rt = 0; rt < 4; rt++)
                #pragma unroll
                for (int ct = 0; ct < 4; ct++)
                    #pragma unroll
                    for (int i = 0; i < 4; i++)
                        Csm[(wr * 64 + rt * 16 + quad * 4 + i) * 132 + wc * 64 + ct * 16 + l15] =
                            f2s(acc[rt][ct][i]);
            drain_barrier();
            #pragma unroll
            for (int it = 0; it < 8; it++) {
                int row = it * 16 + (tid >> 4);
                int chunk = tid & 15;
                bf16x8 v = *(const bf16x8*)(Csm + row * 132 + chunk * 8);
                int hh = ((n0 & 1023) >> 6) + (chunk >> 3);
                int m = m0 + row, b = m >> 11, sp = m & 2047;
                *(bf16x8*)(outB + ((size_t)(b * 16 + hh) * 2048 + sp) * 64 + (chunk & 7) * 8) = v;
            }
        } else {
            // V path: transposed store V^T[b,h,hd,sc]
            const int b = m0 >> 11, h = ((n0 - 1024) >> 6) + wc;
            const int sp = (m0 & 2047) + wr * 64 + quad * 4;
            #pragma unroll
            for (int rt = 0; rt < 4; rt++)
                #pragma unroll
                for (int ct = 0; ct < 4; ct++) {
                    short4 pk;
                    pk.x = f2s(acc[rt][ct][0]); pk.y = f2s(acc[rt][ct][1]);
                    pk.z = f2s(acc[rt][ct][2]); pk.w = f2s(acc[rt][ct][3]);
                    int hd = ct * 16 + l15;
                    *(short4*)(outB2 + ((size_t)(b * 16 + h) * 64 + hd) * 2048 + sp + rt * 16) = pk;
                }
        }
    } else {
        #pragma unroll
        for (int rt = 0; rt < 4; rt++)
            #pragma unroll
            for (int i = 0; i < 4; i++) {
                size_t m = m0 + wr * 64 + rt * 16 + quad * 4 + i;
                #pragma unroll
                for (int ct = 0; ct < 4; ct++) {
                    int n = n0 + wc * 64 + ct * 16 + l15;
                    outF[m * 1024 + n] = acc[rt][ct][i] + bias_vec[n];
                }
            }
    }
}

// ---------------- attention (R4 structure): m97-shaped, LDS-staged K/V ----------------
// S^T = K.Q^T; fixed-max softmax p = exp2(s*0.125*log2e - 8*log2e) (|s|<=8 by LN, RoPE
// norm-preserving). LDS: K 2buf | V 2buf | P 4x(32x72). 50KB.
__global__ __launch_bounds__(256, 3) void attn_kernel(
    const short* __restrict__ Q,   // [64][2048][64]
    const short* __restrict__ K,   // [64][2048][64]
    const short* __restrict__ V,   // [64][64][2048]  (V^T)
    short* __restrict__ AO) {      // [8192][1024] bf16
    __shared__ short smem[8192 + 8192 + 4 * 32 * 72];
    const int tid = threadIdx.x;
    const int w = tid >> 6, lane = tid & 63, quad = lane >> 4, l15 = lane & 15;
    const int bh = blockIdx.x, qt = blockIdx.y;  // grid (64,16): head -> XCD = bh%8
    const short* Qb = Q + (size_t)bh * 2048 * 64;
    const short* Kb = K + (size_t)bh * 2048 * 64;
    const short* Vb = V + (size_t)bh * 64 * 2048;
    short* Pw = smem + 16384 + w * 32 * 72;
    const int q0 = qt * 128 + w * 32;

    const int srow = lane >> 2, slot = lane & 3;
    const int sw = (slot ^ ((srow >> 1) & 3)) * 8;
    const short* Kg = Kb + (size_t)(w * 16 + srow) * 64 + sw;
    const short* Vg = Vb + (size_t)(w * 16 + srow) * 2048 + sw;
    short* Kl0 = smem + w * 512;           // 16 rows/wave/plane
    short* Vl0 = smem + 8192 + w * 512;

    bf16x8 bq[2][2];  // Q as B-operand: B[n=qrow][k=hd]
    #pragma unroll
    for (int nt = 0; nt < 2; nt++)
        #pragma unroll
        for (int ks = 0; ks < 2; ks++)
            bq[nt][ks] = *(const bf16x8*)(Qb + (size_t)(q0 + nt * 16 + l15) * 64 + ks * 32 + quad * 8);

    f32x4 acco[4][2];  // O^T: [ct(hd)][nt(qrow)]
    #pragma unroll
    for (int ct = 0; ct < 4; ct++)
        #pragma unroll
        for (int nt = 0; nt < 2; nt++) acco[ct][nt] = f32x4{0.f, 0.f, 0.f, 0.f};
    float lsum[2] = {0.f, 0.f};
    const int rsw = (l15 >> 1) & 3;
    const int rch = (quad ^ rsw) * 8;

    gload16(Kl0,        Kg);
    gload16(Kl0 + 2048, Kg + 32);
    gload16(Vl0,        Vg);
    gload16(Vl0 + 2048, Vg + 32);
    drain_barrier();

    #pragma unroll 1
    for (int t = 0; t < 32; t++) {
        const int cur = (t & 1) * 4096;
        if (t < 31) {
            const int nxt = 4096 - cur;
            const int sc = (t + 1) * 64;
            gload16(Kl0 + nxt,        Kg + sc * 64);
            gload16(Kl0 + nxt + 2048, Kg + sc * 64 + 32);
            gload16(Vl0 + nxt,        Vg + sc);
            gload16(Vl0 + nxt + 2048, Vg + sc + 32);
        }
        bf16x8 ak[4][2], av[4][2];
        #pragma unroll
        for (int mt = 0; mt < 4; mt++)
            #pragma unroll
            for (int ks = 0; ks < 2; ks++)
                ak[mt][ks] = *(const bf16x8*)(smem + cur + ks * 2048 + (mt * 16 + l15) * 32 + rch);
        #pragma unroll
        for (int ct = 0; ct < 4; ct++)
            #pragma unroll
            for (int ks = 0; ks < 2; ks++)
                av[ct][ks] = *(const bf16x8*)(smem + 8192 + cur + ks * 2048 + (ct * 16 + l15) * 32 + rch);

        #pragma unroll
        for (int mt = 0; mt < 4; mt++) {
            #pragma unroll
            for (int nt = 0; nt < 2; nt++) {
                f32x4 st = f32x4{0.f, 0.f, 0.f, 0.f};
                st = mfma16(ak[mt][0], bq[nt][0], st);
                st = mfma16(ak[mt][1], bq[nt][1], st);
                float e0 = __builtin_amdgcn_exp2f(st[0] * 0.1803368801f - 11.5415605f);
                float e1 = __builtin_amdgcn_exp2f(st[1] * 0.1803368801f - 11.5415605f);
                float e2 = __builtin_amdgcn_exp2f(st[2] * 0.1803368801f - 11.5415605f);
                float e3 = __builtin_amdgcn_exp2f(st[3] * 0.1803368801f - 11.5415605f);
                lsum[nt] += (e0 + e1) + (e2 + e3);
                unsigned int p01 = __builtin_amdgcn_perm(fbits(e1), fbits(e0), 0x07060302u);
                unsigned int p23 = __builtin_amdgcn_perm(fbits(e3), fbits(e2), 0x07060302u);
                uint2 pw;
                pw.x = p01; pw.y = p23;
                *(uint2*)(Pw + (nt * 16 + l15) * 72 + mt * 16 + quad * 4) = pw;
            }
        }
        // P written via uint2*, read via bf16x8* (short-based): TBAA says these
        // never alias, so pin the order with a compiler memory barrier. LDS ops
        // of one wave execute in issue order, so order == correctness here.
        asm volatile("" ::: "memory");
        bf16x8 bp[2][2];
        #pragma unroll
        for (int nt = 0; nt < 2; nt++)
            #pragma unroll
            for (int ks = 0; ks < 2; ks++)
                bp[nt][ks] = *(const bf16x8*)(Pw + (nt * 16 + l15) * 72 + ks * 32 + quad * 8);
        #pragma unroll
        for (int ct = 0; ct < 4; ct++)
            #pragma unroll
            for (int nt = 0; nt < 2; nt++)
                #pragma unroll
                for (int ks = 0; ks < 2; ks++)
                    acco[ct][nt] = mfma16(av[ct][ks], bp[nt][ks], acco[ct][nt]);
        drain_barrier();
    }

    #pragma unroll
    for (int nt = 0; nt < 2; nt++) {
        lsum[nt] += __shfl_xor(lsum[nt], 16, 64);
        lsum[nt] += __shfl_xor(lsum[nt], 32, 64);
    }
    const int b = bh >> 4, h = bh & 15;
    #pragma unroll
    for (int nt = 0; nt < 2; nt++) {
        float inv = 1.f / lsum[nt];
        int sq = q0 + nt * 16 + l15;
        #pragma unroll
        for (int ct = 0; ct < 4; ct++) {
            short4 pk;
            pk.x = f2s(acco[ct][nt][0] * inv); pk.y = f2s(acco[ct][nt][1] * inv);
            pk.z = f2s(acco[ct][nt][2] * inv); pk.w = f2s(acco[ct][nt][3] * inv);
            *(short4*)(AO + ((size_t)b * 2048 + sq) * 1024 + h * 64 + ct * 16 + quad * 4) = pk;
        }
    }
}

extern "C" void kernel_launch(void* const* d_in, const int* in_sizes, int n_in,
                              void* d_out, int out_size, void* d_ws, size_t ws_size,
                              hipStream_t stream) {
    (void)in_sizes; (void)n_in; (void)out_size; (void)ws_size;
    const float* x      = (const float*)d_in[0];
    const float* ctx    = (const float*)d_in[1];
    const float* q_w    = (const float*)d_in[2];
    const float* kv_w   = (const float*)d_in[3];
    const float* qn_s   = (const float*)d_in[4];
    const float* qn_b   = (const float*)d_in[5];
    const float* kn_s   = (const float*)d_in[6];
    const float* kn_b   = (const float*)d_in[7];
    const float* proj_w = (const float*)d_in[8];
    const float* proj_b = (const float*)d_in[9];
    float* out = (float*)d_out;

    char* ws = (char*)d_ws;
    const size_t MB = 1024 * 1024;
    short* xb   = (short*)(ws + 0 * MB);
    short* cb   = (short*)(ws + 16 * MB);
    short* Qb   = (short*)(ws + 32 * MB);   // [64][2048][64] post LN+RoPE
    short* Kb   = (short*)(ws + 48 * MB);   // [64][2048][64] post LN
    short* Vt   = (short*)(ws + 64 * MB);   // [64][64][2048]
    short* AO   = (short*)(ws + 80 * MB);   // [8192][1024]
    short* WqT  = (short*)(ws + 96 * MB);   // 2MB
    short* WkvT = (short*)(ws + 98 * MB);   // 4MB  [2048][1024]
    short* WpT  = (short*)(ws + 102 * MB);  // 2MB

    conv_to_bf16<<<16384, 256, 0, stream>>>(x, ctx, xb, cb);
    transpose_weights<<<dim3(32, 32, 4), 256, 0, stream>>>(q_w, kv_w, proj_w, WqT, WkvT, WpT);
    gemm128<0><<<dim3(8, 64), 256, 0, stream>>>(xb, WqT, qn_s, qn_b, Qb, nullptr, nullptr, nullptr);
    gemm128<1><<<dim3(16, 64), 256, 0, stream>>>(cb, WkvT, kn_s, kn_b, Kb, Vt, nullptr, nullptr);
    attn_kernel<<<dim3(64, 16), 256, 0, stream>>>(Qb, Kb, Vt, AO);
    gemm128<2><<<dim3(8, 64), 256, 0, stream>>>(AO, WpT, nullptr, nullptr, nullptr, nullptr, out, proj_b);
}

// Round 3
// 355.422 us; speedup vs baseline: 1.0059x; 1.0059x over previous
//
#include <hip/hip_runtime.h>
#include <hip/hip_bf16.h>

// CrossAttention R9 = R7 + counted-vmcnt 3-buffer pipeline in gemm128 (T3/T4).
//  - R7 passed at 357.5us: attn 96us (MfmaUtil 31%), GEMMs ~380 TF (worst pool).
//  - gemm128 K-loop: 3 LDS buffers, prefetch t+2, end-of-iter wait is
//    "s_waitcnt vmcnt(4) lgkmcnt(0)" + RAW s_barrier (NOT __syncthreads, which
//    emits a full vmcnt(0) drain). One tile's 4 loads stay in flight across the
//    barrier; per-wave vmcnt(4)+barrier => tile t+1 fully staged by all waves.
//    WAR: a buffer is overwritten >=2 barriers after its last ds_read, and every
//    end-wait includes lgkmcnt(0).
//  - attn unchanged this round (clean attribution).

typedef short bf16x8 __attribute__((ext_vector_type(8)));
typedef float f32x4 __attribute__((ext_vector_type(4)));

__device__ __forceinline__ short f2s(float f) {
    __hip_bfloat16 h = __float2bfloat16(f);
    return __builtin_bit_cast(short, h);
}

__device__ __forceinline__ f32x4 mfma16(bf16x8 a, bf16x8 b, f32x4 c) {
    return __builtin_amdgcn_mfma_f32_16x16x32_bf16(a, b, c, 0, 0, 0);
}

__device__ __forceinline__ void gload16(short* lds, const short* g) {
    __builtin_amdgcn_global_load_lds((const __attribute__((address_space(1))) void*)g,
                                     (__attribute__((address_space(3))) void*)lds,
                                     16, 0, 0);
}

// Full-drain barrier (prologue/epilogue and attn loop).
__device__ __forceinline__ void drain_barrier() {
    asm volatile("s_waitcnt vmcnt(0) lgkmcnt(0)" ::: "memory");
    __syncthreads();
}

__device__ __forceinline__ unsigned int fbits(float f) {
    return __builtin_bit_cast(unsigned int, f);
}

// ---------------- prep: fp32 -> bf16 for activations ----------------
__global__ __launch_bounds__(256) void conv_to_bf16(const float* __restrict__ x,
                                                    const float* __restrict__ ctx,
                                                    short* __restrict__ xb,
                                                    short* __restrict__ cb) {
    const size_t NV = 2097152;
    size_t i = (size_t)blockIdx.x * 256 + threadIdx.x;
    const float4* src = (i < NV) ? (const float4*)x : (const float4*)ctx;
    short* dst = (i < NV) ? xb : cb;
    size_t idx = (i < NV) ? i : i - NV;
    float4 v = src[idx];
    short4 o;
    o.x = f2s(v.x); o.y = f2s(v.y); o.z = f2s(v.z); o.w = f2s(v.w);
    ((short4*)dst)[idx] = o;
}

// ---------------- prep: W -> W^T bf16 (K+V halves contiguous in WkvT) ----------------
__global__ __launch_bounds__(256) void transpose_weights(
    const float* __restrict__ q_w, const float* __restrict__ kv_w,
    const float* __restrict__ proj_w,
    short* __restrict__ WqT, short* __restrict__ WkvT, short* __restrict__ WpT) {
    __shared__ float t[32][33];
    const float* src; short* dst; int ld, coff;
    switch (blockIdx.z) {
        case 0:  src = q_w;    dst = WqT;                 ld = 1024; coff = 0;    break;
        case 1:  src = kv_w;   dst = WkvT;                ld = 2048; coff = 0;    break;
        case 2:  src = kv_w;   dst = WkvT + 1024 * 1024;  ld = 2048; coff = 1024; break;
        default: src = proj_w; dst = WpT;                 ld = 1024; coff = 0;    break;
    }
    int n0 = blockIdx.x * 32, k0 = blockIdx.y * 32;
    int tx = threadIdx.x & 31, ty = threadIdx.x >> 5;
    #pragma unroll
    for (int j = 0; j < 32; j += 8)
        t[ty + j][tx] = src[(size_t)(k0 + ty + j) * ld + coff + n0 + tx];
    __syncthreads();
    #pragma unroll
    for (int j = 0; j < 32; j += 8)
        dst[(size_t)(n0 + ty + j) * 1024 + k0 + tx] = f2s(t[tx][ty + j]);
}

// ---------------- GEMM 128x128, K=1024, 3-buffer counted-vmcnt pipeline ----------------
// MODE 0: Q proj -> per-head LN -> RoPE -> Q[b,h,s,64] bf16 (coalesced via LDS overlay)
// MODE 1: KV proj (N=2048): n0<1024 -> K path (LN -> K[b,h,sc,64]); else V path
//         (V^T[b,h,64,sc] transposed b64 stores)
// MODE 2: out proj -> + bias -> fp32 out
template <int MODE>
__global__ __launch_bounds__(256) void gemm128(
    const short* __restrict__ A,    // [8192][1024] bf16 row-major
    const short* __restrict__ Bt,   // [N][1024] bf16 (N-major, K contiguous)
    const float* __restrict__ ln_scale,
    const float* __restrict__ ln_bias,
    short* __restrict__ outB,
    short* __restrict__ outB2,
    float* __restrict__ outF,
    const float* __restrict__ bias_vec) {
    // staging: 3 bufs x (A 128x32 + B 128x32) = 24576 shorts (48KB);
    // epilogue overlay 128x132 (16896 shorts) fits inside.
    __shared__ short smem[24576];
    const int tid = threadIdx.x;
    const int w = tid >> 6, lane = tid & 63, quad = lane >> 4, l15 = lane & 15;
    const int wr = w & 1, wc = w >> 1;
    const int m0 = blockIdx.y * 128, n0 = blockIdx.x * 128;

    const int srow = lane >> 2, slot = lane & 3;
    const int kslot = (slot ^ ((srow >> 1) & 3)) * 8;  // XOR swizzle: 2-way banks on read
    const short* Ag0 = A + (size_t)(m0 + w * 32 + srow) * 1024 + kslot;
    const short* Ag1 = Ag0 + (size_t)16 * 1024;
    const short* Bg0 = Bt + (size_t)(n0 + w * 32 + srow) * 1024 + kslot;
    const short* Bg1 = Bg0 + (size_t)16 * 1024;
    // wave w stages rows [w*32, w*32+32): 1024 shorts per tile (two 512-short gloads)
    short* Al = smem + w * 1024;           // + buf*8192
    short* Bl = smem + 4096 + w * 1024;    // + buf*8192

    f32x4 acc[4][4];
    #pragma unroll
    for (int r = 0; r < 4; r++)
        #pragma unroll
        for (int c = 0; c < 4; c++) acc[r][c] = f32x4{0.f, 0.f, 0.f, 0.f};

    const int rsw = (l15 >> 1) & 3;
    const int rch = (quad ^ rsw) * 8;

    // prologue: tile 0 -> buf0, tile 1 -> buf1; wait oldest 4 (tile 0) only.
    gload16(Al,              Ag0);
    gload16(Al + 512,        Ag1);
    gload16(Bl,              Bg0);
    gload16(Bl + 512,        Bg1);
    gload16(Al + 8192,       Ag0 + 32);
    gload16(Al + 8192 + 512, Ag1 + 32);
    gload16(Bl + 8192,       Bg0 + 32);
    gload16(Bl + 8192 + 512, Bg1 + 32);
    asm volatile("s_waitcnt vmcnt(4) lgkmcnt(0)" ::: "memory");
    __builtin_amdgcn_s_barrier();

    int curo = 0;       // current compute buffer offset (shorts)
    int pfo = 16384;    // prefetch target buffer offset (tile t+2)
    #pragma unroll 1
    for (int t = 0; t < 32; t++) {
        if (t < 30) {
            const int k0 = (t + 2) * 32;
            gload16(Al + pfo,       Ag0 + k0);
            gload16(Al + pfo + 512, Ag1 + k0);
            gload16(Bl + pfo,       Bg0 + k0);
            gload16(Bl + pfo + 512, Bg1 + k0);
        }
        bf16x8 af[4], bfr[4];
        #pragma unroll
        for (int rt = 0; rt < 4; rt++)
            af[rt] = *(const bf16x8*)(smem + curo + (wr * 64 + rt * 16 + l15) * 32 + rch);
        #pragma unroll
        for (int ct = 0; ct < 4; ct++)
            bfr[ct] = *(const bf16x8*)(smem + curo + 4096 + (wc * 64 + ct * 16 + l15) * 32 + rch);
        #pragma unroll
        for (int rt = 0; rt < 4; rt++)
            #pragma unroll
            for (int ct = 0; ct < 4; ct++)
                acc[rt][ct] = mfma16(af[rt], bfr[ct], acc[rt][ct]);
        // counted wait: tile t+1's 4 loads (oldest) must land; tile t+2's 4 may fly.
        if (t < 30) {
            asm volatile("s_waitcnt vmcnt(4) lgkmcnt(0)" ::: "memory");
        } else {
            asm volatile("s_waitcnt vmcnt(0) lgkmcnt(0)" ::: "memory");
        }
        __builtin_amdgcn_s_barrier();
        curo += 8192; if (curo == 24576) curo = 0;
        pfo  += 8192; if (pfo  == 24576) pfo  = 0;
    }

    // epilogue: lane holds C[row = wr*64+rt*16+quad*4+i][col = wc*64+ct*16+l15]
    const bool vpath = (MODE == 1) && (n0 >= 1024);
    if constexpr (MODE == 0 || MODE == 1) {
        if (!vpath) {
            #pragma unroll
            for (int rt = 0; rt < 4; rt++) {
                #pragma unroll
                for (int i = 0; i < 4; i++) {
                    float s = acc[rt][0][i] + acc[rt][1][i] + acc[rt][2][i] + acc[rt][3][i];
                    float q = acc[rt][0][i] * acc[rt][0][i] + acc[rt][1][i] * acc[rt][1][i] +
                              acc[rt][2][i] * acc[rt][2][i] + acc[rt][3][i] * acc[rt][3][i];
                    #pragma unroll
                    for (int off = 1; off < 16; off <<= 1) {
                        s += __shfl_xor(s, off, 64);
                        q += __shfl_xor(q, off, 64);
                    }
                    float mu = s * (1.f / 64.f);
                    float var = q * (1.f / 64.f) - mu * mu;
                    float rs = rsqrtf(var + 1e-5f);
                    float vals[4];
                    #pragma unroll
                    for (int ct = 0; ct < 4; ct++) {
                        int hd = ct * 16 + l15;
                        vals[ct] = (acc[rt][ct][i] - mu) * rs * ln_scale[hd] + ln_bias[hd];
                    }
                    if constexpr (MODE == 0) {  // RoPE pairs (hd, hd+32) = (ct, ct+2)
                        int sp = (m0 + wr * 64 + rt * 16 + quad * 4 + i) & 2047;
                        #pragma unroll
                        for (int ct = 0; ct < 2; ct++) {
                            int hd1 = ct * 16 + l15;
                            float ang = (float)sp * exp2f((float)hd1 * (-13.287712379549449f / 32.f));
                            float sn, cs;
                            sincosf(ang, &sn, &cs);
                            float v1 = vals[ct], v2 = vals[ct + 2];
                            vals[ct]     = v1 * cs - v2 * sn;
                            vals[ct + 2] = v1 * sn + v2 * cs;
                        }
                    }
                    #pragma unroll
                    for (int ct = 0; ct < 4; ct++) acc[rt][ct][i] = vals[ct];
                }
            }
            drain_barrier();
            short* Csm = smem;  // overlay: [128][132] bf16, +4 pad
            #pragma unroll
            for (int rt = 0; rt < 4; rt++)
                #pragma unroll
                for (int ct = 0; ct < 4; ct++)
                    #pragma unroll
                    for (int i = 0; i < 4; i++)
                        Csm[(wr * 64 + rt * 16 + quad * 4 + i) * 132 + wc * 64 + ct * 16 + l15] =
                            f2s(acc[rt][ct][i]);
            drain_barrier();
            #pragma unroll
            for (int it = 0; it < 8; it++) {
                int row = it * 16 + (tid >> 4);
                int chunk = tid & 15;
                bf16x8 v = *(const bf16x8*)(Csm + row * 132 + chunk * 8);
                int hh = ((n0 & 1023) >> 6) + (chunk >> 3);
                int m = m0 + row, b = m >> 11, sp = m & 2047;
                *(bf16x8*)(outB + ((size_t)(b * 16 + hh) * 2048 + sp) * 64 + (chunk & 7) * 8) = v;
            }
        } else {
            // V path: transposed store V^T[b,h,hd,sc]
            const int b = m0 >> 11, h = ((n0 - 1024) >> 6) + wc;
            const int sp = (m0 & 2047) + wr * 64 + quad * 4;
            #pragma unroll
            for (int rt = 0; rt < 4; rt++)
                #pragma unroll
                for (int ct = 0; ct < 4; ct++) {
                    short4 pk;
                    pk.x = f2s(acc[rt][ct][0]); pk.y = f2s(acc[rt][ct][1]);
                    pk.z = f2s(acc[rt][ct][2]); pk.w = f2s(acc[rt][ct][3]);
                    int hd = ct * 16 + l15;
                    *(short4*)(outB2 + ((size_t)(b * 16 + h) * 64 + hd) * 2048 + sp + rt * 16) = pk;
                }
        }
    } else {
        #pragma unroll
        for (int rt = 0; rt < 4; rt++)
            #pragma unroll
            for (int i = 0; i < 4; i++) {
                size_t m = m0 + wr * 64 + rt * 16 + quad * 4 + i;
                #pragma unroll
                for (int ct = 0; ct < 4; ct++) {
                    int n = n0 + wc * 64 + ct * 16 + l15;
                    outF[m * 1024 + n] = acc[rt][ct][i] + bias_vec[n];
                }
            }
    }
}

// ---------------- attention (R4 structure): m97-shaped, LDS-staged K/V ----------------
// S^T = K.Q^T; fixed-max softmax p = exp2(s*0.125*log2e - 8*log2e) (|s|<=8 by LN, RoPE
// norm-preserving). LDS: K 2buf | V 2buf | P 4x(32x72). 50KB.
__global__ __launch_bounds__(256, 3) void attn_kernel(
    const short* __restrict__ Q,   // [64][2048][64]
    const short* __restrict__ K,   // [64][2048][64]
    const short* __restrict__ V,   // [64][64][2048]  (V^T)
    short* __restrict__ AO) {      // [8192][1024] bf16
    __shared__ short smem[8192 + 8192 + 4 * 32 * 72];
    const int tid = threadIdx.x;
    const int w = tid >> 6, lane = tid & 63, quad = lane >> 4, l15 = lane & 15;
    const int bh = blockIdx.x, qt = blockIdx.y;  // grid (64,16): head -> XCD = bh%8
    const short* Qb = Q + (size_t)bh * 2048 * 64;
    const short* Kb = K + (size_t)bh * 2048 * 64;
    const short* Vb = V + (size_t)bh * 64 * 2048;
    short* Pw = smem + 16384 + w * 32 * 72;
    const int q0 = qt * 128 + w * 32;

    const int srow = lane >> 2, slot = lane & 3;
    const int sw = (slot ^ ((srow >> 1) & 3)) * 8;
    const short* Kg = Kb + (size_t)(w * 16 + srow) * 64 + sw;
    const short* Vg = Vb + (size_t)(w * 16 + srow) * 2048 + sw;
    short* Kl0 = smem + w * 512;           // 16 rows/wave/plane
    short* Vl0 = smem + 8192 + w * 512;

    bf16x8 bq[2][2];  // Q as B-operand: B[n=qrow][k=hd]
    #pragma unroll
    for (int nt = 0; nt < 2; nt++)
        #pragma unroll
        for (int ks = 0; ks < 2; ks++)
            bq[nt][ks] = *(const bf16x8*)(Qb + (size_t)(q0 + nt * 16 + l15) * 64 + ks * 32 + quad * 8);

    f32x4 acco[4][2];  // O^T: [ct(hd)][nt(qrow)]
    #pragma unroll
    for (int ct = 0; ct < 4; ct++)
        #pragma unroll
        for (int nt = 0; nt < 2; nt++) acco[ct][nt] = f32x4{0.f, 0.f, 0.f, 0.f};
    float lsum[2] = {0.f, 0.f};
    const int rsw = (l15 >> 1) & 3;
    const int rch = (quad ^ rsw) * 8;

    gload16(Kl0,        Kg);
    gload16(Kl0 + 2048, Kg + 32);
    gload16(Vl0,        Vg);
    gload16(Vl0 + 2048, Vg + 32);
    drain_barrier();

    #pragma unroll 1
    for (int t = 0; t < 32; t++) {
        const int cur = (t & 1) * 4096;
        if (t < 31) {
            const int nxt = 4096 - cur;
            const int sc = (t + 1) * 64;
            gload16(Kl0 + nxt,        Kg + sc * 64);
            gload16(Kl0 + nxt + 2048, Kg + sc * 64 + 32);
            gload16(Vl0 + nxt,        Vg + sc);
            gload16(Vl0 + nxt + 2048, Vg + sc + 32);
        }
        bf16x8 ak[4][2], av[4][2];
        #pragma unroll
        for (int mt = 0; mt < 4; mt++)
            #pragma unroll
            for (int ks = 0; ks < 2; ks++)
                ak[mt][ks] = *(const bf16x8*)(smem + cur + ks * 2048 + (mt * 16 + l15) * 32 + rch);
        #pragma unroll
        for (int ct = 0; ct < 4; ct++)
            #pragma unroll
            for (int ks = 0; ks < 2; ks++)
                av[ct][ks] = *(const bf16x8*)(smem + 8192 + cur + ks * 2048 + (ct * 16 + l15) * 32 + rch);

        #pragma unroll
        for (int mt = 0; mt < 4; mt++) {
            #pragma unroll
            for (int nt = 0; nt < 2; nt++) {
                f32x4 st = f32x4{0.f, 0.f, 0.f, 0.f};
                st = mfma16(ak[mt][0], bq[nt][0], st);
                st = mfma16(ak[mt][1], bq[nt][1], st);
                float e0 = __builtin_amdgcn_exp2f(st[0] * 0.1803368801f - 11.5415605f);
                float e1 = __builtin_amdgcn_exp2f(st[1] * 0.1803368801f - 11.5415605f);
                float e2 = __builtin_amdgcn_exp2f(st[2] * 0.1803368801f - 11.5415605f);
                float e3 = __builtin_amdgcn_exp2f(st[3] * 0.1803368801f - 11.5415605f);
                lsum[nt] += (e0 + e1) + (e2 + e3);
                unsigned int p01 = __builtin_amdgcn_perm(fbits(e1), fbits(e0), 0x07060302u);
                unsigned int p23 = __builtin_amdgcn_perm(fbits(e3), fbits(e2), 0x07060302u);
                uint2 pw;
                pw.x = p01; pw.y = p23;
                *(uint2*)(Pw + (nt * 16 + l15) * 72 + mt * 16 + quad * 4) = pw;
            }
        }
        // P written via uint2*, read via bf16x8* (short-based): TBAA says these
        // never alias, so pin the order with a compiler memory barrier. LDS ops
        // of one wave execute in issue order, so order == correctness here.
        asm volatile("" ::: "memory");
        bf16x8 bp[2][2];
        #pragma unroll
        for (int nt = 0; nt < 2; nt++)
            #pragma unroll
            for (int ks = 0; ks < 2; ks++)
                bp[nt][ks] = *(const bf16x8*)(Pw + (nt * 16 + l15) * 72 + ks * 32 + quad * 8);
        #pragma unroll
        for (int ct = 0; ct < 4; ct++)
            #pragma unroll
            for (int nt = 0; nt < 2; nt++)
                #pragma unroll
                for (int ks = 0; ks < 2; ks++)
                    acco[ct][nt] = mfma16(av[ct][ks], bp[nt][ks], acco[ct][nt]);
        drain_barrier();
    }

    #pragma unroll
    for (int nt = 0; nt < 2; nt++) {
        lsum[nt] += __shfl_xor(lsum[nt], 16, 64);
        lsum[nt] += __shfl_xor(lsum[nt], 32, 64);
    }
    const int b = bh >> 4, h = bh & 15;
    #pragma unroll
    for (int nt = 0; nt < 2; nt++) {
        float inv = 1.f / lsum[nt];
        int sq = q0 + nt * 16 + l15;
        #pragma unroll
        for (int ct = 0; ct < 4; ct++) {
            short4 pk;
            pk.x = f2s(acco[ct][nt][0] * inv); pk.y = f2s(acco[ct][nt][1] * inv);
            pk.z = f2s(acco[ct][nt][2] * inv); pk.w = f2s(acco[ct][nt][3] * inv);
            *(short4*)(AO + ((size_t)b * 2048 + sq) * 1024 + h * 64 + ct * 16 + quad * 4) = pk;
        }
    }
}

extern "C" void kernel_launch(void* const* d_in, const int* in_sizes, int n_in,
                              void* d_out, int out_size, void* d_ws, size_t ws_size,
                              hipStream_t stream) {
    (void)in_sizes; (void)n_in; (void)out_size; (void)ws_size;
    const float* x      = (const float*)d_in[0];
    const float* ctx    = (const float*)d_in[1];
    const float* q_w    = (const float*)d_in[2];
    const float* kv_w   = (const float*)d_in[3];
    const float* qn_s   = (const float*)d_in[4];
    const float* qn_b   = (const float*)d_in[5];
    const float* kn_s   = (const float*)d_in[6];
    const float* kn_b   = (const float*)d_in[7];
    const float* proj_w = (const float*)d_in[8];
    const float* proj_b = (const float*)d_in[9];
    float* out = (float*)d_out;

    char* ws = (char*)d_ws;
    const size_t MB = 1024 * 1024;
    short* xb   = (short*)(ws + 0 * MB);
    short* cb   = (short*)(ws + 16 * MB);
    short* Qb   = (short*)(ws + 32 * MB);   // [64][2048][64] post LN+RoPE
    short* Kb   = (short*)(ws + 48 * MB);   // [64][2048][64] post LN
    short* Vt   = (short*)(ws + 64 * MB);   // [64][64][2048]
    short* AO   = (short*)(ws + 80 * MB);   // [8192][1024]
    short* WqT  = (short*)(ws + 96 * MB);   // 2MB
    short* WkvT = (short*)(ws + 98 * MB);   // 4MB  [2048][1024]
    short* WpT  = (short*)(ws + 102 * MB);  // 2MB

    conv_to_bf16<<<16384, 256, 0, stream>>>(x, ctx, xb, cb);
    transpose_weights<<<dim3(32, 32, 4), 256, 0, stream>>>(q_w, kv_w, proj_w, WqT, WkvT, WpT);
    gemm128<0><<<dim3(8, 64), 256, 0, stream>>>(xb, WqT, qn_s, qn_b, Qb, nullptr, nullptr, nullptr);
    gemm128<1><<<dim3(16, 64), 256, 0, stream>>>(cb, WkvT, kn_s, kn_b, Kb, Vt, nullptr, nullptr);
    attn_kernel<<<dim3(64, 16), 256, 0, stream>>>(Qb, Kb, Vt, AO);
    gemm128<2><<<dim3(8, 64), 256, 0, stream>>>(AO, WpT, nullptr, nullptr, nullptr, nullptr, out, proj_b);
}

// Round 4
// 329.553 us; speedup vs baseline: 1.0848x; 1.0785x over previous
//
#include <hip/hip_runtime.h>
#include <hip/hip_bf16.h>

// CrossAttention R10 = R9 + attn 2-q-tile persistent blocks + Q-prescale.
//  - R9 post-mortem: counted-vmcnt GEMM graft neutral (regime gate: no fine
//    interleave). Kept as-is; focus moved to attn (only dispatch visible in
//    top-5, 96.8us).
//  - attn diagnosis: Occupancy 25% == (12w phase1 + 4w phase2)/2: grid 1024 at
//    3 blocks/CU leaves a 256-block tail at 1 block/CU for ~half the time.
//  - Fix: grid (64,8), each block processes q-tiles {qt, qt+8} against each
//    staged K/V tile. 512 blocks = 2/CU, all resident, no tail; K/V staging
//    and barriers per unit compute halved. Phases: ak reads -> QK(A,B) ->
//    av reads -> PV(A,B); separate P LDS regions per group (68KB, 2 blk/CU).
//  - Softmax: Q pre-scaled by 0.125*log2e in gemm<0> epilogue; row-constant
//    -11.54 offset dropped (cancels in normalization) -> exp2 arg is raw st.

typedef short bf16x8 __attribute__((ext_vector_type(8)));
typedef float f32x4 __attribute__((ext_vector_type(4)));

__device__ __forceinline__ short f2s(float f) {
    __hip_bfloat16 h = __float2bfloat16(f);
    return __builtin_bit_cast(short, h);
}

__device__ __forceinline__ f32x4 mfma16(bf16x8 a, bf16x8 b, f32x4 c) {
    return __builtin_amdgcn_mfma_f32_16x16x32_bf16(a, b, c, 0, 0, 0);
}

__device__ __forceinline__ void gload16(short* lds, const short* g) {
    __builtin_amdgcn_global_load_lds((const __attribute__((address_space(1))) void*)g,
                                     (__attribute__((address_space(3))) void*)lds,
                                     16, 0, 0);
}

// Barrier with guaranteed counter drain (correctness of single-barrier dbuf).
__device__ __forceinline__ void drain_barrier() {
    asm volatile("s_waitcnt vmcnt(0) lgkmcnt(0)" ::: "memory");
    __syncthreads();
}

__device__ __forceinline__ unsigned int fbits(float f) {
    return __builtin_bit_cast(unsigned int, f);
}

// ---------------- prep: fp32 -> bf16 for activations ----------------
__global__ __launch_bounds__(256) void conv_to_bf16(const float* __restrict__ x,
                                                    const float* __restrict__ ctx,
                                                    short* __restrict__ xb,
                                                    short* __restrict__ cb) {
    const size_t NV = 2097152;
    size_t i = (size_t)blockIdx.x * 256 + threadIdx.x;
    const float4* src = (i < NV) ? (const float4*)x : (const float4*)ctx;
    short* dst = (i < NV) ? xb : cb;
    size_t idx = (i < NV) ? i : i - NV;
    float4 v = src[idx];
    short4 o;
    o.x = f2s(v.x); o.y = f2s(v.y); o.z = f2s(v.z); o.w = f2s(v.w);
    ((short4*)dst)[idx] = o;
}

// ---------------- prep: W -> W^T bf16 (K+V halves contiguous in WkvT) ----------------
__global__ __launch_bounds__(256) void transpose_weights(
    const float* __restrict__ q_w, const float* __restrict__ kv_w,
    const float* __restrict__ proj_w,
    short* __restrict__ WqT, short* __restrict__ WkvT, short* __restrict__ WpT) {
    __shared__ float t[32][33];
    const float* src; short* dst; int ld, coff;
    switch (blockIdx.z) {
        case 0:  src = q_w;    dst = WqT;                 ld = 1024; coff = 0;    break;
        case 1:  src = kv_w;   dst = WkvT;                ld = 2048; coff = 0;    break;
        case 2:  src = kv_w;   dst = WkvT + 1024 * 1024;  ld = 2048; coff = 1024; break;
        default: src = proj_w; dst = WpT;                 ld = 1024; coff = 0;    break;
    }
    int n0 = blockIdx.x * 32, k0 = blockIdx.y * 32;
    int tx = threadIdx.x & 31, ty = threadIdx.x >> 5;
    #pragma unroll
    for (int j = 0; j < 32; j += 8)
        t[ty + j][tx] = src[(size_t)(k0 + ty + j) * ld + coff + n0 + tx];
    __syncthreads();
    #pragma unroll
    for (int j = 0; j < 32; j += 8)
        dst[(size_t)(n0 + ty + j) * 1024 + k0 + tx] = f2s(t[tx][ty + j]);
}

// ---------------- GEMM 128x128, K=1024, 3-buffer counted-vmcnt pipeline ----------------
// MODE 0: Q proj -> per-head LN -> RoPE -> *0.125*log2e -> Q[b,h,s,64] bf16
// MODE 1: KV proj (N=2048): n0<1024 -> K path (LN -> K[b,h,sc,64]); else V path
//         (V^T[b,h,64,sc] transposed b64 stores)
// MODE 2: out proj -> + bias -> fp32 out
template <int MODE>
__global__ __launch_bounds__(256) void gemm128(
    const short* __restrict__ A,    // [8192][1024] bf16 row-major
    const short* __restrict__ Bt,   // [N][1024] bf16 (N-major, K contiguous)
    const float* __restrict__ ln_scale,
    const float* __restrict__ ln_bias,
    short* __restrict__ outB,
    short* __restrict__ outB2,
    float* __restrict__ outF,
    const float* __restrict__ bias_vec) {
    // staging: 3 bufs x (A 128x32 + B 128x32) = 24576 shorts (48KB);
    // epilogue overlay 128x132 (16896 shorts) fits inside.
    __shared__ short smem[24576];
    const int tid = threadIdx.x;
    const int w = tid >> 6, lane = tid & 63, quad = lane >> 4, l15 = lane & 15;
    const int wr = w & 1, wc = w >> 1;
    const int m0 = blockIdx.y * 128, n0 = blockIdx.x * 128;

    const int srow = lane >> 2, slot = lane & 3;
    const int kslot = (slot ^ ((srow >> 1) & 3)) * 8;  // XOR swizzle: 2-way banks on read
    const short* Ag0 = A + (size_t)(m0 + w * 32 + srow) * 1024 + kslot;
    const short* Ag1 = Ag0 + (size_t)16 * 1024;
    const short* Bg0 = Bt + (size_t)(n0 + w * 32 + srow) * 1024 + kslot;
    const short* Bg1 = Bg0 + (size_t)16 * 1024;
    // wave w stages rows [w*32, w*32+32): 1024 shorts per tile (two 512-short gloads)
    short* Al = smem + w * 1024;           // + buf*8192
    short* Bl = smem + 4096 + w * 1024;    // + buf*8192

    f32x4 acc[4][4];
    #pragma unroll
    for (int r = 0; r < 4; r++)
        #pragma unroll
        for (int c = 0; c < 4; c++) acc[r][c] = f32x4{0.f, 0.f, 0.f, 0.f};

    const int rsw = (l15 >> 1) & 3;
    const int rch = (quad ^ rsw) * 8;

    // prologue: tile 0 -> buf0, tile 1 -> buf1; wait oldest 4 (tile 0) only.
    gload16(Al,              Ag0);
    gload16(Al + 512,        Ag1);
    gload16(Bl,              Bg0);
    gload16(Bl + 512,        Bg1);
    gload16(Al + 8192,       Ag0 + 32);
    gload16(Al + 8192 + 512, Ag1 + 32);
    gload16(Bl + 8192,       Bg0 + 32);
    gload16(Bl + 8192 + 512, Bg1 + 32);
    asm volatile("s_waitcnt vmcnt(4) lgkmcnt(0)" ::: "memory");
    __builtin_amdgcn_s_barrier();

    int curo = 0;       // current compute buffer offset (shorts)
    int pfo = 16384;    // prefetch target buffer offset (tile t+2)
    #pragma unroll 1
    for (int t = 0; t < 32; t++) {
        if (t < 30) {
            const int k0 = (t + 2) * 32;
            gload16(Al + pfo,       Ag0 + k0);
            gload16(Al + pfo + 512, Ag1 + k0);
            gload16(Bl + pfo,       Bg0 + k0);
            gload16(Bl + pfo + 512, Bg1 + k0);
        }
        bf16x8 af[4], bfr[4];
        #pragma unroll
        for (int rt = 0; rt < 4; rt++)
            af[rt] = *(const bf16x8*)(smem + curo + (wr * 64 + rt * 16 + l15) * 32 + rch);
        #pragma unroll
        for (int ct = 0; ct < 4; ct++)
            bfr[ct] = *(const bf16x8*)(smem + curo + 4096 + (wc * 64 + ct * 16 + l15) * 32 + rch);
        #pragma unroll
        for (int rt = 0; rt < 4; rt++)
            #pragma unroll
            for (int ct = 0; ct < 4; ct++)
                acc[rt][ct] = mfma16(af[rt], bfr[ct], acc[rt][ct]);
        // counted wait: tile t+1's 4 loads (oldest) must land; tile t+2's 4 may fly.
        if (t < 30) {
            asm volatile("s_waitcnt vmcnt(4) lgkmcnt(0)" ::: "memory");
        } else {
            asm volatile("s_waitcnt vmcnt(0) lgkmcnt(0)" ::: "memory");
        }
        __builtin_amdgcn_s_barrier();
        curo += 8192; if (curo == 24576) curo = 0;
        pfo  += 8192; if (pfo  == 24576) pfo  = 0;
    }

    // epilogue: lane holds C[row = wr*64+rt*16+quad*4+i][col = wc*64+ct*16+l15]
    const bool vpath = (MODE == 1) && (n0 >= 1024);
    if constexpr (MODE == 0 || MODE == 1) {
        if (!vpath) {
            #pragma unroll
            for (int rt = 0; rt < 4; rt++) {
                #pragma unroll
                for (int i = 0; i < 4; i++) {
                    float s = acc[rt][0][i] + acc[rt][1][i] + acc[rt][2][i] + acc[rt][3][i];
                    float q = acc[rt][0][i] * acc[rt][0][i] + acc[rt][1][i] * acc[rt][1][i] +
                              acc[rt][2][i] * acc[rt][2][i] + acc[rt][3][i] * acc[rt][3][i];
                    #pragma unroll
                    for (int off = 1; off < 16; off <<= 1) {
                        s += __shfl_xor(s, off, 64);
                        q += __shfl_xor(q, off, 64);
                    }
                    float mu = s * (1.f / 64.f);
                    float var = q * (1.f / 64.f) - mu * mu;
                    float rs = rsqrtf(var + 1e-5f);
                    float vals[4];
                    #pragma unroll
                    for (int ct = 0; ct < 4; ct++) {
                        int hd = ct * 16 + l15;
                        vals[ct] = (acc[rt][ct][i] - mu) * rs * ln_scale[hd] + ln_bias[hd];
                    }
                    if constexpr (MODE == 0) {  // RoPE pairs (hd, hd+32) = (ct, ct+2)
                        int sp = (m0 + wr * 64 + rt * 16 + quad * 4 + i) & 2047;
                        #pragma unroll
                        for (int ct = 0; ct < 2; ct++) {
                            int hd1 = ct * 16 + l15;
                            float ang = (float)sp * exp2f((float)hd1 * (-13.287712379549449f / 32.f));
                            float sn, cs;
                            sincosf(ang, &sn, &cs);
                            float v1 = vals[ct], v2 = vals[ct + 2];
                            vals[ct]     = v1 * cs - v2 * sn;
                            vals[ct + 2] = v1 * sn + v2 * cs;
                        }
                        // fold softmax scale*log2e into Q: attn exp2 arg = raw dot
                        #pragma unroll
                        for (int ct = 0; ct < 4; ct++) vals[ct] *= 0.1803368801f;
                    }
                    #pragma unroll
                    for (int ct = 0; ct < 4; ct++) acc[rt][ct][i] = vals[ct];
                }
            }
            drain_barrier();
            short* Csm = smem;  // overlay: [128][132] bf16, +4 pad
            #pragma unroll
            for (int rt = 0; rt < 4; rt++)
                #pragma unroll
                for (int ct = 0; ct < 4; ct++)
                    #pragma unroll
                    for (int i = 0; i < 4; i++)
                        Csm[(wr * 64 + rt * 16 + quad * 4 + i) * 132 + wc * 64 + ct * 16 + l15] =
                            f2s(acc[rt][ct][i]);
            drain_barrier();
            #pragma unroll
            for (int it = 0; it < 8; it++) {
                int row = it * 16 + (tid >> 4);
                int chunk = tid & 15;
                bf16x8 v = *(const bf16x8*)(Csm + row * 132 + chunk * 8);
                int hh = ((n0 & 1023) >> 6) + (chunk >> 3);
                int m = m0 + row, b = m >> 11, sp = m & 2047;
                *(bf16x8*)(outB + ((size_t)(b * 16 + hh) * 2048 + sp) * 64 + (chunk & 7) * 8) = v;
            }
        } else {
            // V path: transposed store V^T[b,h,hd,sc]
            const int b = m0 >> 11, h = ((n0 - 1024) >> 6) + wc;
            const int sp = (m0 & 2047) + wr * 64 + quad * 4;
            #pragma unroll
            for (int rt = 0; rt < 4; rt++)
                #pragma unroll
                for (int ct = 0; ct < 4; ct++) {
                    short4 pk;
                    pk.x = f2s(acc[rt][ct][0]); pk.y = f2s(acc[rt][ct][1]);
                    pk.z = f2s(acc[rt][ct][2]); pk.w = f2s(acc[rt][ct][3]);
                    int hd = ct * 16 + l15;
                    *(short4*)(outB2 + ((size_t)(b * 16 + h) * 64 + hd) * 2048 + sp + rt * 16) = pk;
                }
        }
    } else {
        #pragma unroll
        for (int rt = 0; rt < 4; rt++)
            #pragma unroll
            for (int i = 0; i < 4; i++) {
                size_t m = m0 + wr * 64 + rt * 16 + quad * 4 + i;
                #pragma unroll
                for (int ct = 0; ct < 4; ct++) {
                    int n = n0 + wc * 64 + ct * 16 + l15;
                    outF[m * 1024 + n] = acc[rt][ct][i] + bias_vec[n];
                }
            }
    }
}

// ---------------- attention: 2 q-tiles per block, tail-free ----------------
// S^T = K.Q^T with Q pre-scaled by 0.125*log2e -> p = exp2(st) (row-constant
// offset dropped; cancels in normalization; |st|<=11.6, p<=3000, fp32 sums fine).
// grid (64,8): block handles q-tiles {qt, qt+8}. LDS: K 2buf | V 2buf |
// P_A 4x(32x72) | P_B 4x(32x72) = 68KB -> 2 blocks/CU, 512 blocks all resident.
__global__ __launch_bounds__(256, 2) void attn_kernel(
    const short* __restrict__ Q,   // [64][2048][64]
    const short* __restrict__ K,   // [64][2048][64]
    const short* __restrict__ V,   // [64][64][2048]  (V^T)
    short* __restrict__ AO) {      // [8192][1024] bf16
    __shared__ short smem[8192 + 8192 + 2 * 4 * 32 * 72];
    const int tid = threadIdx.x;
    const int w = tid >> 6, lane = tid & 63, quad = lane >> 4, l15 = lane & 15;
    const int bh = blockIdx.x, qt = blockIdx.y;  // grid (64,8): head -> XCD = bh%8
    const short* Qb = Q + (size_t)bh * 2048 * 64;
    const short* Kb = K + (size_t)bh * 2048 * 64;
    const short* Vb = V + (size_t)bh * 64 * 2048;
    const int q0g[2] = {qt * 128 + w * 32, (qt + 8) * 128 + w * 32};

    const int srow = lane >> 2, slot = lane & 3;
    const int sw = (slot ^ ((srow >> 1) & 3)) * 8;
    const short* Kg = Kb + (size_t)(w * 16 + srow) * 64 + sw;
    const short* Vg = Vb + (size_t)(w * 16 + srow) * 2048 + sw;
    short* Kl0 = smem + w * 512;           // 16 rows/wave/plane
    short* Vl0 = smem + 8192 + w * 512;

    bf16x8 bq[2][2][2];  // [group][nt][ks]: Q as B-operand B[n=qrow][k=hd]
    #pragma unroll
    for (int g = 0; g < 2; g++)
        #pragma unroll
        for (int nt = 0; nt < 2; nt++)
            #pragma unroll
            for (int ks = 0; ks < 2; ks++)
                bq[g][nt][ks] =
                    *(const bf16x8*)(Qb + (size_t)(q0g[g] + nt * 16 + l15) * 64 + ks * 32 + quad * 8);

    f32x4 acco[2][4][2];  // [group][ct(hd)][nt(qrow)] O^T
    #pragma unroll
    for (int g = 0; g < 2; g++)
        #pragma unroll
        for (int ct = 0; ct < 4; ct++)
            #pragma unroll
            for (int nt = 0; nt < 2; nt++) acco[g][ct][nt] = f32x4{0.f, 0.f, 0.f, 0.f};
    float lsum[2][2] = {{0.f, 0.f}, {0.f, 0.f}};
    const int rsw = (l15 >> 1) & 3;
    const int rch = (quad ^ rsw) * 8;

    gload16(Kl0,        Kg);
    gload16(Kl0 + 2048, Kg + 32);
    gload16(Vl0,        Vg);
    gload16(Vl0 + 2048, Vg + 32);
    drain_barrier();

    #pragma unroll 1
    for (int t = 0; t < 32; t++) {
        const int cur = (t & 1) * 4096;
        if (t < 31) {
            const int nxt = 4096 - cur;
            const int sc = (t + 1) * 64;
            gload16(Kl0 + nxt,        Kg + sc * 64);
            gload16(Kl0 + nxt + 2048, Kg + sc * 64 + 32);
            gload16(Vl0 + nxt,        Vg + sc);
            gload16(Vl0 + nxt + 2048, Vg + sc + 32);
        }
        // ---- phase 1: K fragments, QK^T + exp2 + P stores for both groups ----
        bf16x8 ak[4][2];
        #pragma unroll
        for (int mt = 0; mt < 4; mt++)
            #pragma unroll
            for (int ks = 0; ks < 2; ks++)
                ak[mt][ks] = *(const bf16x8*)(smem + cur + ks * 2048 + (mt * 16 + l15) * 32 + rch);

        #pragma unroll
        for (int g = 0; g < 2; g++) {
            short* Pw = smem + 16384 + g * 9216 + w * 2304;
            #pragma unroll
            for (int mt = 0; mt < 4; mt++) {
                #pragma unroll
                for (int nt = 0; nt < 2; nt++) {
                    f32x4 st = f32x4{0.f, 0.f, 0.f, 0.f};
                    st = mfma16(ak[mt][0], bq[g][nt][0], st);
                    st = mfma16(ak[mt][1], bq[g][nt][1], st);
                    float e0 = __builtin_amdgcn_exp2f(st[0]);
                    float e1 = __builtin_amdgcn_exp2f(st[1]);
                    float e2 = __builtin_amdgcn_exp2f(st[2]);
                    float e3 = __builtin_amdgcn_exp2f(st[3]);
                    lsum[g][nt] += (e0 + e1) + (e2 + e3);
                    unsigned int p01 = __builtin_amdgcn_perm(fbits(e1), fbits(e0), 0x07060302u);
                    unsigned int p23 = __builtin_amdgcn_perm(fbits(e3), fbits(e2), 0x07060302u);
                    uint2 pw;
                    pw.x = p01; pw.y = p23;
                    *(uint2*)(Pw + (nt * 16 + l15) * 72 + mt * 16 + quad * 4) = pw;
                }
            }
        }
        // P written via uint2*, read via bf16x8*: fence pins program order
        // (wave-local LDS ops execute in issue order -> order == correctness).
        asm volatile("" ::: "memory");

        // ---- phase 2: V fragments, P reads + PV for both groups ----
        bf16x8 av[4][2];
        #pragma unroll
        for (int ct = 0; ct < 4; ct++)
            #pragma unroll
            for (int ks = 0; ks < 2; ks++)
                av[ct][ks] = *(const bf16x8*)(smem + 8192 + cur + ks * 2048 + (ct * 16 + l15) * 32 + rch);

        #pragma unroll
        for (int g = 0; g < 2; g++) {
            short* Pw = smem + 16384 + g * 9216 + w * 2304;
            bf16x8 bp[2][2];
            #pragma unroll
            for (int nt = 0; nt < 2; nt++)
                #pragma unroll
                for (int ks = 0; ks < 2; ks++)
                    bp[nt][ks] = *(const bf16x8*)(Pw + (nt * 16 + l15) * 72 + ks * 32 + quad * 8);
            #pragma unroll
            for (int ct = 0; ct < 4; ct++)
                #pragma unroll
                for (int nt = 0; nt < 2; nt++)
                    #pragma unroll
                    for (int ks = 0; ks < 2; ks++)
                        acco[g][ct][nt] = mfma16(av[ct][ks], bp[nt][ks], acco[g][ct][nt]);
        }
        drain_barrier();
    }

    #pragma unroll
    for (int g = 0; g < 2; g++)
        #pragma unroll
        for (int nt = 0; nt < 2; nt++) {
            lsum[g][nt] += __shfl_xor(lsum[g][nt], 16, 64);
            lsum[g][nt] += __shfl_xor(lsum[g][nt], 32, 64);
        }
    const int b = bh >> 4, h = bh & 15;
    #pragma unroll
    for (int g = 0; g < 2; g++)
        #pragma unroll
        for (int nt = 0; nt < 2; nt++) {
            float inv = 1.f / lsum[g][nt];
            int sq = q0g[g] + nt * 16 + l15;
            #pragma unroll
            for (int ct = 0; ct < 4; ct++) {
                short4 pk;
                pk.x = f2s(acco[g][ct][nt][0] * inv); pk.y = f2s(acco[g][ct][nt][1] * inv);
                pk.z = f2s(acco[g][ct][nt][2] * inv); pk.w = f2s(acco[g][ct][nt][3] * inv);
                *(short4*)(AO + ((size_t)b * 2048 + sq) * 1024 + h * 64 + ct * 16 + quad * 4) = pk;
            }
        }
}

extern "C" void kernel_launch(void* const* d_in, const int* in_sizes, int n_in,
                              void* d_out, int out_size, void* d_ws, size_t ws_size,
                              hipStream_t stream) {
    (void)in_sizes; (void)n_in; (void)out_size; (void)ws_size;
    const float* x      = (const float*)d_in[0];
    const float* ctx    = (const float*)d_in[1];
    const float* q_w    = (const float*)d_in[2];
    const float* kv_w   = (const float*)d_in[3];
    const float* qn_s   = (const float*)d_in[4];
    const float* qn_b   = (const float*)d_in[5];
    const float* kn_s   = (const float*)d_in[6];
    const float* kn_b   = (const float*)d_in[7];
    const float* proj_w = (const float*)d_in[8];
    const float* proj_b = (const float*)d_in[9];
    float* out = (float*)d_out;

    char* ws = (char*)d_ws;
    const size_t MB = 1024 * 1024;
    short* xb   = (short*)(ws + 0 * MB);
    short* cb   = (short*)(ws + 16 * MB);
    short* Qb   = (short*)(ws + 32 * MB);   // [64][2048][64] post LN+RoPE+scale
    short* Kb   = (short*)(ws + 48 * MB);   // [64][2048][64] post LN
    short* Vt   = (short*)(ws + 64 * MB);   // [64][64][2048]
    short* AO   = (short*)(ws + 80 * MB);   // [8192][1024]
    short* WqT  = (short*)(ws + 96 * MB);   // 2MB
    short* WkvT = (short*)(ws + 98 * MB);   // 4MB  [2048][1024]
    short* WpT  = (short*)(ws + 102 * MB);  // 2MB

    conv_to_bf16<<<16384, 256, 0, stream>>>(x, ctx, xb, cb);
    transpose_weights<<<dim3(32, 32, 4), 256, 0, stream>>>(q_w, kv_w, proj_w, WqT, WkvT, WpT);
    gemm128<0><<<dim3(8, 64), 256, 0, stream>>>(xb, WqT, qn_s, qn_b, Qb, nullptr, nullptr, nullptr);
    gemm128<1><<<dim3(16, 64), 256, 0, stream>>>(cb, WkvT, kn_s, kn_b, Kb, Vt, nullptr, nullptr);
    attn_kernel<<<dim3(64, 8), 256, 0, stream>>>(Qb, Kb, Vt, AO);
    gemm128<2><<<dim3(8, 64), 256, 0, stream>>>(AO, WpT, nullptr, nullptr, nullptr, nullptr, out, proj_b);
}